// Round 4
// baseline (5081.785 us; speedup 1.0000x reference)
//
#include <hip/hip_runtime.h>
#include <stdint.h>

typedef __attribute__((ext_vector_type(8))) short short8;
typedef __attribute__((ext_vector_type(4))) float f32x4;
typedef __attribute__((ext_vector_type(4))) unsigned int u32x4;

#define B_    32
#define T_    512
#define E_    300
#define KE_   320
#define H_    1024
#define G4_   4096
#define R_    30
#define AD_   350
#define AC_   384
#define MH_   512
#define FEAT_ 61440
#define NWG_  64      // workgroups per direction
#define NU_   16      // hidden units per workgroup

__device__ __forceinline__ unsigned short f2bu(float f) {
  unsigned int x = __builtin_bit_cast(unsigned int, f);
  x += 0x7fffu + ((x >> 16) & 1u);
  return (unsigned short)(x >> 16);
}
__device__ __forceinline__ float b2f(unsigned short u) {
  return __builtin_bit_cast(float, (unsigned int)u << 16);
}
// fast activations: v_exp_f32 + v_rcp_f32 (≈1ulp; bf16 output has huge slack)
__device__ __forceinline__ float sigm(float x) {
  return __builtin_amdgcn_rcpf(1.f + __expf(-x));
}
__device__ __forceinline__ float tanh_fast(float x) {
  return 1.f - 2.f * __builtin_amdgcn_rcpf(1.f + __expf(2.f * x));
}

// ---------------------------------------------------------------------------
// K0: cast/pad inputs to bf16: xb[16384][320], wihb[8192][320], w1b[384][2048]
// ---------------------------------------------------------------------------
__global__ void k0_prep(const int* __restrict__ inp, const float* __restrict__ W_emb,
                        const float* __restrict__ W_ih, const float* __restrict__ W1,
                        unsigned short* __restrict__ xb, unsigned short* __restrict__ wihb,
                        unsigned short* __restrict__ w1b) {
  const int N1 = 16384 * KE_;
  const int N2 = 8192 * KE_;
  const int N3 = AC_ * 2048;
  const int NT = N1 + N2 + N3;
  for (int i = blockIdx.x * blockDim.x + threadIdx.x; i < NT; i += gridDim.x * blockDim.x) {
    if (i < N1) {
      int row = i / KE_, e = i - row * KE_;
      float v = (e < E_) ? W_emb[(size_t)inp[row] * E_ + e] : 0.f;
      xb[i] = f2bu(v);
    } else if (i < N1 + N2) {
      int j = i - N1;
      int rw = j / KE_, e = j - rw * KE_;
      float v = (e < E_) ? W_ih[(size_t)rw * E_ + e] : 0.f;
      wihb[j] = f2bu(v);
    } else {
      int j = i - N1 - N2;
      int a = j >> 11, k = j & 2047;
      float v = (a < AD_) ? W1[(size_t)a * 2048 + k] : 0.f;
      w1b[j] = f2bu(v);
    }
  }
}

// ---------------------------------------------------------------------------
// K1: xw[t][R][b] (bf16) = Wihb[R][:] . xb[b*512+t][:] + b_ih[R] + b_hh[R]
// ---------------------------------------------------------------------------
__global__ __launch_bounds__(256, 1) void k1_xw(const unsigned short* __restrict__ wihb,
                                                const unsigned short* __restrict__ xb,
                                                const float* __restrict__ b_ih,
                                                const float* __restrict__ b_hh,
                                                unsigned short* __restrict__ xw) {
  const int rb = blockIdx.x;
  const int tb = blockIdx.y;
  const int wid = threadIdx.x >> 6, lane = threadIdx.x & 63;
  const int l15 = lane & 15, lg = lane >> 4;

  f32x4 acc[2][8];
#pragma unroll
  for (int mi = 0; mi < 2; ++mi)
#pragma unroll
    for (int nt = 0; nt < 8; ++nt) acc[mi][nt] = (f32x4){0.f, 0.f, 0.f, 0.f};

#pragma unroll
  for (int kt = 0; kt < 10; ++kt) {
    short8 a0 = *(const short8*)(wihb + (size_t)(rb * 128 + (wid * 2 + 0) * 16 + l15) * KE_ + kt * 32 + lg * 8);
    short8 a1 = *(const short8*)(wihb + (size_t)(rb * 128 + (wid * 2 + 1) * 16 + l15) * KE_ + kt * 32 + lg * 8);
#pragma unroll
    for (int nt = 0; nt < 8; ++nt) {
      int c = nt * 16 + l15;
      int row = (c & 31) * T_ + tb * 4 + (c >> 5);
      short8 bf = *(const short8*)(xb + (size_t)row * KE_ + kt * 32 + lg * 8);
      acc[0][nt] = __builtin_amdgcn_mfma_f32_16x16x32_bf16(a0, bf, acc[0][nt], 0, 0, 0);
      acc[1][nt] = __builtin_amdgcn_mfma_f32_16x16x32_bf16(a1, bf, acc[1][nt], 0, 0, 0);
    }
  }

#pragma unroll
  for (int mi = 0; mi < 2; ++mi) {
#pragma unroll
    for (int j = 0; j < 4; ++j) {
      int R = rb * 128 + (wid * 2 + mi) * 16 + lg * 4 + j;
      float bias = b_ih[R] + b_hh[R];
#pragma unroll
      for (int nt = 0; nt < 8; ++nt) {
        int c = nt * 16 + l15;
        int t = tb * 4 + (c >> 5);
        int b = c & 31;
        xw[((size_t)t * 8192 + R) * 32 + b] = f2bu(acc[mi][nt][j] + bias);
      }
    }
  }
}

// ---------------------------------------------------------------------------
// K2 v4: persistent bidirectional LSTM, canary-flag protocol.
//   - producer: 1KB h store (sc0 sc1) -> vmcnt(0) -> 4B canary store
//   - consumer: polls 64 canaries (256B/wave, cheap) then ONE bulk h load
//   - fast exp/rcp activations; stride-21 LDS reduce
// ---------------------------------------------------------------------------
__global__ __launch_bounds__(256, 1) void k2_rnn(const float* __restrict__ Whh,
                                                 const unsigned short* __restrict__ xw,
                                                 unsigned short* __restrict__ outb,
                                                 int* __restrict__ cans) {
  const int dir = blockIdx.x >> 6;
  const int w = blockIdx.x & 63;
  const int tid = threadIdx.x;
  const int wid = tid >> 6, lane = tid & 63;
  const int l15 = lane & 15, lg = lane >> 4;

  __shared__ float Gp[4][4][32][21];               // [wave][gate][batch][unit+pad21]
  __shared__ __align__(16) unsigned short htmp[32][16];

  // ---- preload W_hh slice into registers as bf16 A-fragments -----------
  short8 afr[4][8];
  {
    const int kq = wid << 8;
#pragma unroll
    for (int g = 0; g < 4; ++g) {
      const float* wp = Whh + ((size_t)dir * G4_ + g * H_ + w * NU_ + l15) * H_ + kq + lg * 8;
#pragma unroll
      for (int ktl = 0; ktl < 8; ++ktl) {
        float4 f0 = *(const float4*)(wp + ktl * 32);
        float4 f1 = *(const float4*)(wp + ktl * 32 + 4);
        short8 s;
        s[0] = (short)f2bu(f0.x); s[1] = (short)f2bu(f0.y);
        s[2] = (short)f2bu(f0.z); s[3] = (short)f2bu(f0.w);
        s[4] = (short)f2bu(f1.x); s[5] = (short)f2bu(f1.y);
        s[6] = (short)f2bu(f1.z); s[7] = (short)f2bu(f1.w);
        afr[g][ktl] = s;
      }
    }
  }

  // B-fragment row base pointers into outb (batch rows l15 and l15+16)
  const unsigned short* rb0 = outb + (size_t)l15 * T_ * 2048 + dir * H_ + (wid << 8) + lg * 8;
  const unsigned short* rb1 = outb + (size_t)(l15 + 16) * T_ * 2048 + dir * H_ + (wid << 8) + lg * 8;

  const int u = tid >> 5;    // activation role: unit pair (u, u+8)
  const int b = tid & 31;    // activation role: batch
  float cst[2] = {0.f, 0.f};

#pragma unroll 1
  for (int s = 0; s < T_; ++s) {
    const int t = dir ? (T_ - 1 - s) : s;

    // -- prefetch xw (input projection + bias), independent of h ---------
    unsigned short xwv[2][4];
    {
      const unsigned short* xwt = xw + (size_t)t * 8192 * 32;
#pragma unroll
      for (int p = 0; p < 2; ++p)
#pragma unroll
        for (int g = 0; g < 4; ++g)
          xwv[p][g] = xwt[(size_t)(dir * G4_ + g * H_ + w * NU_ + u + p * 8) * 32 + b];
    }

    f32x4 acc[4][2];
#pragma unroll
    for (int g = 0; g < 4; ++g) {
      acc[g][0] = (f32x4){0.f, 0.f, 0.f, 0.f};
      acc[g][1] = (f32x4){0.f, 0.f, 0.f, 0.f};
    }

    if (s > 0) {
      const int tsrc = dir ? t + 1 : t - 1;

      // -- cheap detect: 64 canaries, one per producer, lane i -> WG i ----
      {
        const int* cp = cans + ((size_t)dir * T_ + tsrc) * 64 + lane;
        int v, guard = 0;
        for (;;) {
          asm volatile("global_load_dword %0, %1, off sc0 sc1\n\ts_waitcnt vmcnt(0)"
                       : "=v"(v) : "v"(cp) : "memory");
          if (__all(v != 0)) break;
          if (++guard > 50000) break;   // hang safety; never trips co-resident
        }
      }

      // -- bulk load of h^T B-fragments, exactly once ---------------------
      const unsigned short* a0 = rb0 + (size_t)tsrc * 2048;
      const unsigned short* a1 = rb1 + (size_t)tsrc * 2048;
      u32x4 q0, q1, q2, q3, q4, q5, q6, q7, q8, q9, qa, qb, qc, qd, qe, qf;
      asm volatile(
          "global_load_dwordx4 %0, %16, off sc0 sc1\n\t"
          "global_load_dwordx4 %1, %16, off offset:64 sc0 sc1\n\t"
          "global_load_dwordx4 %2, %16, off offset:128 sc0 sc1\n\t"
          "global_load_dwordx4 %3, %16, off offset:192 sc0 sc1\n\t"
          "global_load_dwordx4 %4, %16, off offset:256 sc0 sc1\n\t"
          "global_load_dwordx4 %5, %16, off offset:320 sc0 sc1\n\t"
          "global_load_dwordx4 %6, %16, off offset:384 sc0 sc1\n\t"
          "global_load_dwordx4 %7, %16, off offset:448 sc0 sc1\n\t"
          "global_load_dwordx4 %8, %17, off sc0 sc1\n\t"
          "global_load_dwordx4 %9, %17, off offset:64 sc0 sc1\n\t"
          "global_load_dwordx4 %10, %17, off offset:128 sc0 sc1\n\t"
          "global_load_dwordx4 %11, %17, off offset:192 sc0 sc1\n\t"
          "global_load_dwordx4 %12, %17, off offset:256 sc0 sc1\n\t"
          "global_load_dwordx4 %13, %17, off offset:320 sc0 sc1\n\t"
          "global_load_dwordx4 %14, %17, off offset:384 sc0 sc1\n\t"
          "global_load_dwordx4 %15, %17, off offset:448 sc0 sc1\n\t"
          "s_waitcnt vmcnt(0)"
          : "=&v"(q0), "=&v"(q1), "=&v"(q2), "=&v"(q3), "=&v"(q4), "=&v"(q5),
            "=&v"(q6), "=&v"(q7), "=&v"(q8), "=&v"(q9), "=&v"(qa), "=&v"(qb),
            "=&v"(qc), "=&v"(qd), "=&v"(qe), "=&v"(qf)
          : "v"(a0), "v"(a1)
          : "memory");
      __builtin_amdgcn_sched_barrier(0);

      short8 bf0[8], bf1[8];
      bf0[0] = __builtin_bit_cast(short8, q0); bf0[1] = __builtin_bit_cast(short8, q1);
      bf0[2] = __builtin_bit_cast(short8, q2); bf0[3] = __builtin_bit_cast(short8, q3);
      bf0[4] = __builtin_bit_cast(short8, q4); bf0[5] = __builtin_bit_cast(short8, q5);
      bf0[6] = __builtin_bit_cast(short8, q6); bf0[7] = __builtin_bit_cast(short8, q7);
      bf1[0] = __builtin_bit_cast(short8, q8); bf1[1] = __builtin_bit_cast(short8, q9);
      bf1[2] = __builtin_bit_cast(short8, qa); bf1[3] = __builtin_bit_cast(short8, qb);
      bf1[4] = __builtin_bit_cast(short8, qc); bf1[5] = __builtin_bit_cast(short8, qd);
      bf1[6] = __builtin_bit_cast(short8, qe); bf1[7] = __builtin_bit_cast(short8, qf);

#pragma unroll
      for (int ktl = 0; ktl < 8; ++ktl) {
#pragma unroll
        for (int g = 0; g < 4; ++g) {
          acc[g][0] = __builtin_amdgcn_mfma_f32_16x16x32_bf16(afr[g][ktl], bf0[ktl], acc[g][0], 0, 0, 0);
          acc[g][1] = __builtin_amdgcn_mfma_f32_16x16x32_bf16(afr[g][ktl], bf1[ktl], acc[g][1], 0, 0, 0);
        }
      }
    }

    // -- write K-partial sums to LDS (scalar, stride-21: conflict-free) --
#pragma unroll
    for (int g = 0; g < 4; ++g)
#pragma unroll
      for (int n = 0; n < 2; ++n)
#pragma unroll
        for (int j = 0; j < 4; ++j)
          Gp[wid][g][n * 16 + l15][lg * 4 + j] = acc[g][n][j];
    __syncthreads();

    // -- activations: thread handles (u,b) and (u+8,b) -------------------
#pragma unroll
    for (int p = 0; p < 2; ++p) {
      int ul = u + p * 8;
      float gi = Gp[0][0][b][ul] + Gp[1][0][b][ul] + Gp[2][0][b][ul] + Gp[3][0][b][ul] + b2f(xwv[p][0]);
      float gf = Gp[0][1][b][ul] + Gp[1][1][b][ul] + Gp[2][1][b][ul] + Gp[3][1][b][ul] + b2f(xwv[p][1]);
      float gg = Gp[0][2][b][ul] + Gp[1][2][b][ul] + Gp[2][2][b][ul] + Gp[3][2][b][ul] + b2f(xwv[p][2]);
      float go = Gp[0][3][b][ul] + Gp[1][3][b][ul] + Gp[2][3][b][ul] + Gp[3][3][b][ul] + b2f(xwv[p][3]);
      cst[p] = sigm(gf) * cst[p] + sigm(gi) * tanh_fast(gg);
      float hv = sigm(go) * tanh_fast(cst[p]);
      htmp[b][ul] = f2bu(hv);
    }
    __syncthreads();

    // -- wave 0: publish h, drain, then set this WG's canary -------------
    if (tid < 64) {
      int bb = tid >> 1, half = tid & 1;
      u32x4 v = *(const u32x4*)&htmp[bb][half * 8];
      unsigned short* hp = outb + ((size_t)bb * T_ + t) * 2048 + dir * H_ + w * NU_ + half * 8;
      asm volatile("global_store_dwordx4 %0, %1, off sc0 sc1\n\ts_waitcnt vmcnt(0)"
                   :: "v"(hp), "v"(v) : "memory");
      if (tid == 0) {
        int one = 1;
        const int* cp = cans + ((size_t)dir * T_ + t) * 64 + w;
        asm volatile("global_store_dword %0, %1, off sc0 sc1" :: "v"(cp), "v"(one) : "memory");
      }
    }
    // no trailing barrier: next step's canary-wait gates everything
  }
}

// ---------------------------------------------------------------------------
// K3: th1[row][a] = tanh( out[row][:] . W1b[a][:] )
// ---------------------------------------------------------------------------
__global__ __launch_bounds__(256, 1) void k3_s1(const unsigned short* __restrict__ outb,
                                                const unsigned short* __restrict__ w1b,
                                                unsigned short* __restrict__ th1) {
  const int rb = blockIdx.x;
  const int wid = threadIdx.x >> 6, lane = threadIdx.x & 63;
  const int m = wid & 1, nh = wid >> 1;
  const int l15 = lane & 15, lg = lane >> 4;

  f32x4 acc[12];
#pragma unroll
  for (int nt = 0; nt < 12; ++nt) acc[nt] = (f32x4){0.f, 0.f, 0.f, 0.f};

  const unsigned short* arow = outb + ((size_t)rb * 32 + m * 16 + l15) * 2048;
  for (int kt = 0; kt < 64; ++kt) {
    short8 af = *(const short8*)(arow + kt * 32 + lg * 8);
#pragma unroll
    for (int nt = 0; nt < 12; ++nt) {
      int col = nh * 192 + nt * 16 + l15;
      short8 bf = *(const short8*)(w1b + (size_t)col * 2048 + kt * 32 + lg * 8);
      acc[nt] = __builtin_amdgcn_mfma_f32_16x16x32_bf16(af, bf, acc[nt], 0, 0, 0);
    }
  }
#pragma unroll
  for (int nt = 0; nt < 12; ++nt) {
#pragma unroll
    for (int j = 0; j < 4; ++j) {
      int row = rb * 32 + m * 16 + lg * 4 + j;
      int col = nh * 192 + nt * 16 + l15;
      th1[(size_t)row * AC_ + col] = f2bu(tanhf(acc[nt][j]));
    }
  }
}

// ---------------------------------------------------------------------------
// K4: abuf[b][r][t] = th1[row][:350] . W2[r][:350]
// ---------------------------------------------------------------------------
__global__ void k4_s2(const unsigned short* __restrict__ th1, const float* __restrict__ W2,
                      float* __restrict__ abuf) {
  int idx = blockIdx.x * 256 + threadIdx.x;
  int row = idx >> 5, r = idx & 31;
  if (r >= R_) return;
  const unsigned short* tp = th1 + (size_t)row * AC_;
  const float* wp = W2 + r * AD_;
  float acc = 0.f;
  for (int a = 0; a < AD_; ++a) acc = fmaf(b2f(tp[a]), wp[a], acc);
  int b = row >> 9, t = row & 511;
  abuf[((size_t)b * R_ + r) * T_ + t] = acc;
}

// ---------------------------------------------------------------------------
// K5: masked softmax over t (in place).  One wave per (b,r).
// ---------------------------------------------------------------------------
__global__ void k5_sm(float* __restrict__ abuf, const int* __restrict__ lens) {
  int wv = blockIdx.x * 4 + (threadIdx.x >> 6);
  int lane = threadIdx.x & 63;
  if (wv >= B_ * R_) return;
  int b = wv / R_, r = wv % R_;
  int len = lens[b];
  float* row = abuf + ((size_t)b * R_ + r) * T_;
  float v[8];
  float mx = -1e30f;
#pragma unroll
  for (int i = 0; i < 8; ++i) {
    int t = lane + i * 64;
    float x = (t < len) ? row[t] : -1e30f;
    v[i] = x;
    mx = fmaxf(mx, x);
  }
#pragma unroll
  for (int o = 32; o > 0; o >>= 1) mx = fmaxf(mx, __shfl_xor(mx, o));
  float sum = 0.f;
#pragma unroll
  for (int i = 0; i < 8; ++i) {
    float e = (v[i] > -1e29f) ? __expf(v[i] - mx) : 0.f;
    v[i] = e;
    sum += e;
  }
#pragma unroll
  for (int o = 32; o > 0; o >>= 1) sum += __shfl_xor(sum, o);
  float inv = 1.f / sum;
#pragma unroll
  for (int i = 0; i < 8; ++i) row[lane + i * 64] = v[i] * inv;
}

// ---------------------------------------------------------------------------
// K6: M[b][r][h] = sum_t A[b][r][t] * out[b][t][h].
// ---------------------------------------------------------------------------
__global__ __launch_bounds__(256) void k6_m(const float* __restrict__ abuf,
                                            const unsigned short* __restrict__ outb,
                                            float* __restrict__ mbuf) {
  int b = blockIdx.x >> 4, hb = blockIdx.x & 15;
  __shared__ float As[R_ * T_];
  for (int i = threadIdx.x; i < R_ * T_; i += 256) As[i] = abuf[(size_t)b * R_ * T_ + i];
  __syncthreads();
  int h = threadIdx.x & 127, rh = threadIdx.x >> 7;
  float acc[15];
#pragma unroll
  for (int rr = 0; rr < 15; ++rr) acc[rr] = 0.f;
  const unsigned short* op = outb + (size_t)b * T_ * 2048 + hb * 128 + h;
  for (int t = 0; t < T_; ++t) {
    float vv = b2f(op[(size_t)t * 2048]);
#pragma unroll
    for (int rr = 0; rr < 15; ++rr) acc[rr] = fmaf(As[(rh * 15 + rr) * T_ + t], vv, acc[rr]);
  }
#pragma unroll
  for (int rr = 0; rr < 15; ++rr)
    mbuf[(size_t)b * FEAT_ + (size_t)(rh * 15 + rr) * 2048 + hb * 128 + h] = acc[rr];
}

// ---------------------------------------------------------------------------
// K7: per-sample penalty partial: ||A A^T - I||_F^2.
// ---------------------------------------------------------------------------
__global__ __launch_bounds__(256) void k7_pen(const float* __restrict__ abuf,
                                              float* __restrict__ penp) {
  int b = blockIdx.x;
  __shared__ float As[R_ * 515];
  __shared__ float red[256];
  for (int i = threadIdx.x; i < R_ * T_; i += 256) {
    int r = i >> 9, t = i & 511;
    As[r * 515 + t] = abuf[(size_t)b * R_ * T_ + i];
  }
  __syncthreads();
  float psum = 0.f;
  for (int p = threadIdx.x; p < R_ * R_; p += 256) {
    int r = p / R_, s = p % R_;
    const float* pr = As + r * 515;
    const float* ps = As + s * 515;
    float d = 0.f;
    for (int t = 0; t < T_; ++t) d = fmaf(pr[t], ps[t], d);
    d -= (r == s) ? 1.f : 0.f;
    psum += d * d;
  }
  red[threadIdx.x] = psum;
  __syncthreads();
  for (int o = 128; o > 0; o >>= 1) {
    if (threadIdx.x < o) red[threadIdx.x] += red[threadIdx.x + o];
    __syncthreads();
  }
  if (threadIdx.x == 0) penp[b] = red[0];
}

// ---------------------------------------------------------------------------
// K8: hid[b][m] = relu( feats[b][:] . W_mlp[m][:] + b_mlp[m] ).  (R1 form)
// ---------------------------------------------------------------------------
__global__ __launch_bounds__(256) void k8_mlp(const float* __restrict__ feats,
                                              const float* __restrict__ W_mlp,
                                              const float* __restrict__ b_mlp,
                                              float* __restrict__ hid) {
  int mblk = blockIdx.x >> 2, bblk = blockIdx.x & 3;
  int oi = threadIdx.x >> 1, ks = threadIdx.x & 1;
  int m = mblk * 16 + (oi >> 3);
  int b = bblk * 8 + (oi & 7);
  const float* fp = feats + (size_t)b * FEAT_;
  const float* wp = W_mlp + (size_t)m * FEAT_;
  float acc = 0.f;
  for (int i = 0; i < FEAT_ / 8; ++i) {
    int k = i * 8 + ks * 4;
    float4 wv = *(const float4*)(wp + k);
    float4 fv = *(const float4*)(fp + k);
    acc = fmaf(wv.x, fv.x, acc);
    acc = fmaf(wv.y, fv.y, acc);
    acc = fmaf(wv.z, fv.z, acc);
    acc = fmaf(wv.w, fv.w, acc);
  }
  float other = __shfl_xor(acc, 1);
  if (ks == 0) {
    float tot = acc + other + b_mlp[m];
    hid[(size_t)b * MH_ + m] = fmaxf(tot, 0.f);
  }
}

// ---------------------------------------------------------------------------
// K9: decoded = softmax(hid @ W_dec^T + b_dec); penal = mean(penp).
// ---------------------------------------------------------------------------
__global__ void k9_out(const float* __restrict__ hid, const float* __restrict__ W_dec,
                       const float* __restrict__ b_dec, const float* __restrict__ penp,
                       float* __restrict__ out) {
  int tid = threadIdx.x;
  if (tid < 64) {
    int b = tid >> 1, c = tid & 1;
    const float* hp = hid + (size_t)b * MH_;
    const float* wp = W_dec + (size_t)c * MH_;
    float acc = b_dec[c];
    for (int k = 0; k < MH_; ++k) acc = fmaf(hp[k], wp[k], acc);
    float other = __shfl_xor(acc, 1);
    float mx = fmaxf(acc, other);
    float e = __expf(acc - mx), eo = __expf(other - mx);
    out[b * 2 + c] = e / (e + eo);
  } else if (tid == 64) {
    float s = 0.f;
    for (int b = 0; b < B_; ++b) s += penp[b];
    out[64] = s * (1.f / 32.f);
  }
}

// ---------------------------------------------------------------------------
extern "C" void kernel_launch(void* const* d_in, const int* in_sizes, int n_in,
                              void* d_out, int out_size, void* d_ws, size_t ws_size,
                              hipStream_t stream) {
  const int* inp = (const int*)d_in[0];
  const int* lens = (const int*)d_in[1];
  const float* W_emb = (const float*)d_in[2];
  const float* W_ih = (const float*)d_in[3];
  const float* W_hh = (const float*)d_in[4];
  const float* b_ih = (const float*)d_in[5];
  const float* b_hh = (const float*)d_in[6];
  const float* W1 = (const float*)d_in[7];
  const float* W2 = (const float*)d_in[8];
  const float* W_mlp = (const float*)d_in[9];
  const float* b_mlp = (const float*)d_in[10];
  const float* W_dec = (const float*)d_in[11];
  const float* b_dec = (const float*)d_in[12];
  float* out = (float*)d_out;

  char* ws = (char*)d_ws;
  size_t off = 0;
  auto take = [&](size_t bytes) -> char* {
    char* p = ws + off;
    off = (off + bytes + 255) & ~(size_t)255;
    return p;
  };
  unsigned short* xw = (unsigned short*)take((size_t)T_ * 8192 * 32 * 2);       // 268.4 MB
  unsigned short* outb = (unsigned short*)take((size_t)B_ * T_ * 2048 * 2);     // 67.1 MB
  unsigned short* xb = (unsigned short*)take((size_t)16384 * KE_ * 2);          // 10.5 MB
  unsigned short* wihb = (unsigned short*)take((size_t)8192 * KE_ * 2);         // 5.2 MB
  unsigned short* w1b = (unsigned short*)take((size_t)AC_ * 2048 * 2);          // 1.6 MB
  unsigned short* th1 = (unsigned short*)take((size_t)16384 * AC_ * 2);         // 12.6 MB
  float* abuf = (float*)take((size_t)B_ * R_ * T_ * 4);                         // 2.0 MB
  float* mbuf = (float*)take((size_t)B_ * FEAT_ * 4);                           // 7.9 MB
  float* penp = (float*)take(B_ * 4);
  float* hid = (float*)take((size_t)B_ * MH_ * 4);
  int* cans = (int*)take((size_t)2 * T_ * 64 * 4);                              // 256 KB

  if (off > ws_size) {  // unambiguous failure signal: NaN output
    hipMemsetAsync(d_out, 0xFF, (size_t)out_size * 4, stream);
    return;
  }

  hipMemsetAsync(cans, 0, (size_t)2 * T_ * 64 * 4, stream);

  k0_prep<<<2048, 256, 0, stream>>>(inp, W_emb, W_ih, W1, xb, wihb, w1b);
  k1_xw<<<dim3(64, 128), 256, 0, stream>>>(wihb, xb, b_ih, b_hh, xw);
  k2_rnn<<<128, 256, 0, stream>>>(W_hh, xw, outb, cans);
  k3_s1<<<512, 256, 0, stream>>>(outb, w1b, th1);
  k4_s2<<<2048, 256, 0, stream>>>(th1, W2, abuf);
  k5_sm<<<240, 256, 0, stream>>>(abuf, lens);
  k6_m<<<512, 256, 0, stream>>>(abuf, outb, mbuf);
  k7_pen<<<32, 256, 0, stream>>>(abuf, penp);
  k8_mlp<<<128, 256, 0, stream>>>(mbuf, W_mlp, b_mlp, hid);
  k9_out<<<1, 128, 0, stream>>>(hid, W_dec, b_dec, penp, out);
}

// Round 5
// 4172.097 us; speedup vs baseline: 1.2180x; 1.2180x over previous
//
#include <hip/hip_runtime.h>
#include <stdint.h>

typedef __attribute__((ext_vector_type(8))) short short8;
typedef __attribute__((ext_vector_type(4))) float f32x4;
typedef __attribute__((ext_vector_type(4))) unsigned int u32x4;

#define B_    32
#define T_    512
#define E_    300
#define KE_   320
#define H_    1024
#define G4_   4096
#define R_    30
#define AD_   350
#define AC_   384
#define MH_   512
#define FEAT_ 61440
#define NWG_  64      // workgroups per direction
#define NU_   16      // hidden units per workgroup

__device__ __forceinline__ unsigned short f2bu(float f) {
  unsigned int x = __builtin_bit_cast(unsigned int, f);
  x += 0x7fffu + ((x >> 16) & 1u);
  return (unsigned short)(x >> 16);
}
__device__ __forceinline__ float b2f(unsigned short u) {
  return __builtin_bit_cast(float, (unsigned int)u << 16);
}
// fast activations: v_exp_f32 + v_rcp_f32 (≈1ulp; bf16 output has huge slack)
__device__ __forceinline__ float sigm(float x) {
  return __builtin_amdgcn_rcpf(1.f + __expf(-x));
}
__device__ __forceinline__ float tanh_fast(float x) {
  return 1.f - 2.f * __builtin_amdgcn_rcpf(1.f + __expf(2.f * x));
}

// ---------------------------------------------------------------------------
// K0: cast/pad inputs to bf16: xb[16384][320], wihb[8192][320], w1b[384][2048]
// ---------------------------------------------------------------------------
__global__ void k0_prep(const int* __restrict__ inp, const float* __restrict__ W_emb,
                        const float* __restrict__ W_ih, const float* __restrict__ W1,
                        unsigned short* __restrict__ xb, unsigned short* __restrict__ wihb,
                        unsigned short* __restrict__ w1b) {
  const int N1 = 16384 * KE_;
  const int N2 = 8192 * KE_;
  const int N3 = AC_ * 2048;
  const int NT = N1 + N2 + N3;
  for (int i = blockIdx.x * blockDim.x + threadIdx.x; i < NT; i += gridDim.x * blockDim.x) {
    if (i < N1) {
      int row = i / KE_, e = i - row * KE_;
      float v = (e < E_) ? W_emb[(size_t)inp[row] * E_ + e] : 0.f;
      xb[i] = f2bu(v);
    } else if (i < N1 + N2) {
      int j = i - N1;
      int rw = j / KE_, e = j - rw * KE_;
      float v = (e < E_) ? W_ih[(size_t)rw * E_ + e] : 0.f;
      wihb[j] = f2bu(v);
    } else {
      int j = i - N1 - N2;
      int a = j >> 11, k = j & 2047;
      float v = (a < AD_) ? W1[(size_t)a * 2048 + k] : 0.f;
      w1b[j] = f2bu(v);
    }
  }
}

// ---------------------------------------------------------------------------
// K1: xw[t][R][b] (bf16) = Wihb[R][:] . xb[b*512+t][:] + b_ih[R] + b_hh[R]
// ---------------------------------------------------------------------------
__global__ __launch_bounds__(256, 1) void k1_xw(const unsigned short* __restrict__ wihb,
                                                const unsigned short* __restrict__ xb,
                                                const float* __restrict__ b_ih,
                                                const float* __restrict__ b_hh,
                                                unsigned short* __restrict__ xw) {
  const int rb = blockIdx.x;
  const int tb = blockIdx.y;
  const int wid = threadIdx.x >> 6, lane = threadIdx.x & 63;
  const int l15 = lane & 15, lg = lane >> 4;

  f32x4 acc[2][8];
#pragma unroll
  for (int mi = 0; mi < 2; ++mi)
#pragma unroll
    for (int nt = 0; nt < 8; ++nt) acc[mi][nt] = (f32x4){0.f, 0.f, 0.f, 0.f};

#pragma unroll
  for (int kt = 0; kt < 10; ++kt) {
    short8 a0 = *(const short8*)(wihb + (size_t)(rb * 128 + (wid * 2 + 0) * 16 + l15) * KE_ + kt * 32 + lg * 8);
    short8 a1 = *(const short8*)(wihb + (size_t)(rb * 128 + (wid * 2 + 1) * 16 + l15) * KE_ + kt * 32 + lg * 8);
#pragma unroll
    for (int nt = 0; nt < 8; ++nt) {
      int c = nt * 16 + l15;
      int row = (c & 31) * T_ + tb * 4 + (c >> 5);
      short8 bf = *(const short8*)(xb + (size_t)row * KE_ + kt * 32 + lg * 8);
      acc[0][nt] = __builtin_amdgcn_mfma_f32_16x16x32_bf16(a0, bf, acc[0][nt], 0, 0, 0);
      acc[1][nt] = __builtin_amdgcn_mfma_f32_16x16x32_bf16(a1, bf, acc[1][nt], 0, 0, 0);
    }
  }

#pragma unroll
  for (int mi = 0; mi < 2; ++mi) {
#pragma unroll
    for (int j = 0; j < 4; ++j) {
      int R = rb * 128 + (wid * 2 + mi) * 16 + lg * 4 + j;
      float bias = b_ih[R] + b_hh[R];
#pragma unroll
      for (int nt = 0; nt < 8; ++nt) {
        int c = nt * 16 + l15;
        int t = tb * 4 + (c >> 5);
        int b = c & 31;
        xw[((size_t)t * 8192 + R) * 32 + b] = f2bu(acc[mi][nt][j] + bias);
      }
    }
  }
}

// ---------------------------------------------------------------------------
// K2 v5: persistent bidirectional LSTM, thin-poll-on-data protocol.
//   - producer: bare sc0 sc1 h store into outb slot (no drain, no canary)
//   - consumer: thin poll (1 dword per producer, 256B/wave, sentinel bit14)
//               -> ONE cached bulk load (L2-deduped across WGs on the XCD)
//               -> full validate; rare sc0 sc1 retry as correctness backstop
//   - outb sentinel-initialized to 0xFF each launch (bit14 set = unwritten)
// ---------------------------------------------------------------------------
__global__ __launch_bounds__(256, 1) void k2_rnn(const float* __restrict__ Whh,
                                                 const unsigned short* __restrict__ xw,
                                                 unsigned short* __restrict__ outb) {
  const int dir = blockIdx.x >> 6;
  const int w = blockIdx.x & 63;
  const int tid = threadIdx.x;
  const int wid = tid >> 6, lane = tid & 63;
  const int l15 = lane & 15, lg = lane >> 4;

  __shared__ float Gp[4][4][32][21];               // [wave][gate][batch][unit+pad21]
  __shared__ __align__(16) unsigned short htmp[32][16];

  // ---- preload W_hh slice into registers as bf16 A-fragments -----------
  short8 afr[4][8];
  {
    const int kq = wid << 8;
#pragma unroll
    for (int g = 0; g < 4; ++g) {
      const float* wp = Whh + ((size_t)dir * G4_ + g * H_ + w * NU_ + l15) * H_ + kq + lg * 8;
#pragma unroll
      for (int ktl = 0; ktl < 8; ++ktl) {
        float4 f0 = *(const float4*)(wp + ktl * 32);
        float4 f1 = *(const float4*)(wp + ktl * 32 + 4);
        short8 s;
        s[0] = (short)f2bu(f0.x); s[1] = (short)f2bu(f0.y);
        s[2] = (short)f2bu(f0.z); s[3] = (short)f2bu(f0.w);
        s[4] = (short)f2bu(f1.x); s[5] = (short)f2bu(f1.y);
        s[6] = (short)f2bu(f1.z); s[7] = (short)f2bu(f1.w);
        afr[g][ktl] = s;
      }
    }
  }

  // B-fragment row base pointers into outb (batch rows l15 and l15+16)
  const unsigned short* rb0 = outb + (size_t)l15 * T_ * 2048 + dir * H_ + (wid << 8) + lg * 8;
  const unsigned short* rb1 = outb + (size_t)(l15 + 16) * T_ * 2048 + dir * H_ + (wid << 8) + lg * 8;

  const int u = tid >> 5;    // activation role: unit pair (u, u+8)
  const int b = tid & 31;    // activation role: batch
  float cst[2] = {0.f, 0.f};

#pragma unroll 1
  for (int s = 0; s < T_; ++s) {
    const int t = dir ? (T_ - 1 - s) : s;

    // -- prefetch xw (input projection + bias), independent of h ---------
    unsigned short xwv[2][4];
    {
      const unsigned short* xwt = xw + (size_t)t * 8192 * 32;
#pragma unroll
      for (int p = 0; p < 2; ++p)
#pragma unroll
        for (int g = 0; g < 4; ++g)
          xwv[p][g] = xwt[(size_t)(dir * G4_ + g * H_ + w * NU_ + u + p * 8) * 32 + b];
    }

    f32x4 acc[4][2];
#pragma unroll
    for (int g = 0; g < 4; ++g) {
      acc[g][0] = (f32x4){0.f, 0.f, 0.f, 0.f};
      acc[g][1] = (f32x4){0.f, 0.f, 0.f, 0.f};
    }

    if (s > 0) {
      const int tsrc = dir ? t + 1 : t - 1;

      // -- thin poll: lane i samples 1 dword of producer i's slice (b=0) --
      {
        const unsigned short* sp = outb + (size_t)tsrc * 2048 + dir * H_ + lane * NU_;
        unsigned v;
        int guard = 0;
        for (;;) {
          asm volatile("global_load_dword %0, %1, off sc0 sc1\n\ts_waitcnt vmcnt(0)"
                       : "=v"(v) : "v"(sp) : "memory");
          if (__all(!(v & 0x40004000u))) break;
          if (++guard > 50000) break;   // hang safety; never trips co-resident
        }
      }

      // -- bulk payload: ONE cached load pass (L2-dedup), then validate ---
      const unsigned short* a0 = rb0 + (size_t)tsrc * 2048;
      const unsigned short* a1 = rb1 + (size_t)tsrc * 2048;
      u32x4 q0, q1, q2, q3, q4, q5, q6, q7, q8, q9, qa, qb, qc, qd, qe, qf;
      q0 = *(const u32x4*)(a0 + 0 * 32);  q1 = *(const u32x4*)(a0 + 1 * 32);
      q2 = *(const u32x4*)(a0 + 2 * 32);  q3 = *(const u32x4*)(a0 + 3 * 32);
      q4 = *(const u32x4*)(a0 + 4 * 32);  q5 = *(const u32x4*)(a0 + 5 * 32);
      q6 = *(const u32x4*)(a0 + 6 * 32);  q7 = *(const u32x4*)(a0 + 7 * 32);
      q8 = *(const u32x4*)(a1 + 0 * 32);  q9 = *(const u32x4*)(a1 + 1 * 32);
      qa = *(const u32x4*)(a1 + 2 * 32);  qb = *(const u32x4*)(a1 + 3 * 32);
      qc = *(const u32x4*)(a1 + 4 * 32);  qd = *(const u32x4*)(a1 + 5 * 32);
      qe = *(const u32x4*)(a1 + 6 * 32);  qf = *(const u32x4*)(a1 + 7 * 32);
      {
        u32x4 o01 = q0 | q1, o23 = q2 | q3, o45 = q4 | q5, o67 = q6 | q7;
        u32x4 o89 = q8 | q9, oab = qa | qb, ocd = qc | qd, oef = qe | qf;
        u32x4 ov4 = ((o01 | o23) | (o45 | o67)) | ((o89 | oab) | (ocd | oef));
        unsigned ov = (ov4[0] | ov4[1]) | (ov4[2] | ov4[3]);
        if (__builtin_expect((ov & 0x40004000u) != 0, 0)) {
          // backstop: straggler store or stale L2 line -> sc0 sc1 reload loop
          int guard = 0;
          for (;;) {
            asm volatile(
                "global_load_dwordx4 %0, %16, off sc0 sc1\n\t"
                "global_load_dwordx4 %1, %16, off offset:64 sc0 sc1\n\t"
                "global_load_dwordx4 %2, %16, off offset:128 sc0 sc1\n\t"
                "global_load_dwordx4 %3, %16, off offset:192 sc0 sc1\n\t"
                "global_load_dwordx4 %4, %16, off offset:256 sc0 sc1\n\t"
                "global_load_dwordx4 %5, %16, off offset:320 sc0 sc1\n\t"
                "global_load_dwordx4 %6, %16, off offset:384 sc0 sc1\n\t"
                "global_load_dwordx4 %7, %16, off offset:448 sc0 sc1\n\t"
                "global_load_dwordx4 %8, %17, off sc0 sc1\n\t"
                "global_load_dwordx4 %9, %17, off offset:64 sc0 sc1\n\t"
                "global_load_dwordx4 %10, %17, off offset:128 sc0 sc1\n\t"
                "global_load_dwordx4 %11, %17, off offset:192 sc0 sc1\n\t"
                "global_load_dwordx4 %12, %17, off offset:256 sc0 sc1\n\t"
                "global_load_dwordx4 %13, %17, off offset:320 sc0 sc1\n\t"
                "global_load_dwordx4 %14, %17, off offset:384 sc0 sc1\n\t"
                "global_load_dwordx4 %15, %17, off offset:448 sc0 sc1\n\t"
                "s_waitcnt vmcnt(0)"
                : "=&v"(q0), "=&v"(q1), "=&v"(q2), "=&v"(q3), "=&v"(q4), "=&v"(q5),
                  "=&v"(q6), "=&v"(q7), "=&v"(q8), "=&v"(q9), "=&v"(qa), "=&v"(qb),
                  "=&v"(qc), "=&v"(qd), "=&v"(qe), "=&v"(qf)
                : "v"(a0), "v"(a1)
                : "memory");
            u32x4 r01 = q0 | q1, r23 = q2 | q3, r45 = q4 | q5, r67 = q6 | q7;
            u32x4 r89 = q8 | q9, rab = qa | qb, rcd = qc | qd, ref_ = qe | qf;
            u32x4 rv4 = ((r01 | r23) | (r45 | r67)) | ((r89 | rab) | (rcd | ref_));
            unsigned rv = (rv4[0] | rv4[1]) | (rv4[2] | rv4[3]);
            if (!(rv & 0x40004000u)) break;
            if (++guard > 50000) break;
          }
        }
      }

      short8 bf0[8], bf1[8];
      bf0[0] = __builtin_bit_cast(short8, q0); bf0[1] = __builtin_bit_cast(short8, q1);
      bf0[2] = __builtin_bit_cast(short8, q2); bf0[3] = __builtin_bit_cast(short8, q3);
      bf0[4] = __builtin_bit_cast(short8, q4); bf0[5] = __builtin_bit_cast(short8, q5);
      bf0[6] = __builtin_bit_cast(short8, q6); bf0[7] = __builtin_bit_cast(short8, q7);
      bf1[0] = __builtin_bit_cast(short8, q8); bf1[1] = __builtin_bit_cast(short8, q9);
      bf1[2] = __builtin_bit_cast(short8, qa); bf1[3] = __builtin_bit_cast(short8, qb);
      bf1[4] = __builtin_bit_cast(short8, qc); bf1[5] = __builtin_bit_cast(short8, qd);
      bf1[6] = __builtin_bit_cast(short8, qe); bf1[7] = __builtin_bit_cast(short8, qf);

#pragma unroll
      for (int ktl = 0; ktl < 8; ++ktl) {
#pragma unroll
        for (int g = 0; g < 4; ++g) {
          acc[g][0] = __builtin_amdgcn_mfma_f32_16x16x32_bf16(afr[g][ktl], bf0[ktl], acc[g][0], 0, 0, 0);
          acc[g][1] = __builtin_amdgcn_mfma_f32_16x16x32_bf16(afr[g][ktl], bf1[ktl], acc[g][1], 0, 0, 0);
        }
      }
    }

    // -- write K-partial sums to LDS (scalar, stride-21: conflict-free) --
#pragma unroll
    for (int g = 0; g < 4; ++g)
#pragma unroll
      for (int n = 0; n < 2; ++n)
#pragma unroll
        for (int j = 0; j < 4; ++j)
          Gp[wid][g][n * 16 + l15][lg * 4 + j] = acc[g][n][j];
    __syncthreads();

    // -- activations: thread handles (u,b) and (u+8,b) -------------------
#pragma unroll
    for (int p = 0; p < 2; ++p) {
      int ul = u + p * 8;
      float gi = Gp[0][0][b][ul] + Gp[1][0][b][ul] + Gp[2][0][b][ul] + Gp[3][0][b][ul] + b2f(xwv[p][0]);
      float gf = Gp[0][1][b][ul] + Gp[1][1][b][ul] + Gp[2][1][b][ul] + Gp[3][1][b][ul] + b2f(xwv[p][1]);
      float gg = Gp[0][2][b][ul] + Gp[1][2][b][ul] + Gp[2][2][b][ul] + Gp[3][2][b][ul] + b2f(xwv[p][2]);
      float go = Gp[0][3][b][ul] + Gp[1][3][b][ul] + Gp[2][3][b][ul] + Gp[3][3][b][ul] + b2f(xwv[p][3]);
      cst[p] = sigm(gf) * cst[p] + sigm(gi) * tanh_fast(gg);
      float hv = sigm(go) * tanh_fast(cst[p]);
      htmp[b][ul] = f2bu(hv);
    }
    __syncthreads();

    // -- wave 0: publish h into outb slot; the data IS the flag ----------
    if (tid < 64) {
      int bb = tid >> 1, half = tid & 1;
      u32x4 v = *(const u32x4*)&htmp[bb][half * 8];
      unsigned short* hp = outb + ((size_t)bb * T_ + t) * 2048 + dir * H_ + w * NU_ + half * 8;
      asm volatile("global_store_dwordx4 %0, %1, off sc0 sc1" :: "v"(hp), "v"(v) : "memory");
    }
    // no trailing barrier: next step's thin-poll + validate gate everything
  }
}

// ---------------------------------------------------------------------------
// K3: th1[row][a] = tanh( out[row][:] . W1b[a][:] )
// ---------------------------------------------------------------------------
__global__ __launch_bounds__(256, 1) void k3_s1(const unsigned short* __restrict__ outb,
                                                const unsigned short* __restrict__ w1b,
                                                unsigned short* __restrict__ th1) {
  const int rb = blockIdx.x;
  const int wid = threadIdx.x >> 6, lane = threadIdx.x & 63;
  const int m = wid & 1, nh = wid >> 1;
  const int l15 = lane & 15, lg = lane >> 4;

  f32x4 acc[12];
#pragma unroll
  for (int nt = 0; nt < 12; ++nt) acc[nt] = (f32x4){0.f, 0.f, 0.f, 0.f};

  const unsigned short* arow = outb + ((size_t)rb * 32 + m * 16 + l15) * 2048;
  for (int kt = 0; kt < 64; ++kt) {
    short8 af = *(const short8*)(arow + kt * 32 + lg * 8);
#pragma unroll
    for (int nt = 0; nt < 12; ++nt) {
      int col = nh * 192 + nt * 16 + l15;
      short8 bf = *(const short8*)(w1b + (size_t)col * 2048 + kt * 32 + lg * 8);
      acc[nt] = __builtin_amdgcn_mfma_f32_16x16x32_bf16(af, bf, acc[nt], 0, 0, 0);
    }
  }
#pragma unroll
  for (int nt = 0; nt < 12; ++nt) {
#pragma unroll
    for (int j = 0; j < 4; ++j) {
      int row = rb * 32 + m * 16 + lg * 4 + j;
      int col = nh * 192 + nt * 16 + l15;
      th1[(size_t)row * AC_ + col] = f2bu(tanh_fast(acc[nt][j]));
    }
  }
}

// ---------------------------------------------------------------------------
// K4: abuf[b][r][t] = th1[row][:350] . W2[r][:350]
// ---------------------------------------------------------------------------
__global__ void k4_s2(const unsigned short* __restrict__ th1, const float* __restrict__ W2,
                      float* __restrict__ abuf) {
  int idx = blockIdx.x * 256 + threadIdx.x;
  int row = idx >> 5, r = idx & 31;
  if (r >= R_) return;
  const unsigned short* tp = th1 + (size_t)row * AC_;
  const float* wp = W2 + r * AD_;
  float acc = 0.f;
  for (int a = 0; a < AD_; ++a) acc = fmaf(b2f(tp[a]), wp[a], acc);
  int b = row >> 9, t = row & 511;
  abuf[((size_t)b * R_ + r) * T_ + t] = acc;
}

// ---------------------------------------------------------------------------
// K5: masked softmax over t (in place).  One wave per (b,r).
// ---------------------------------------------------------------------------
__global__ void k5_sm(float* __restrict__ abuf, const int* __restrict__ lens) {
  int wv = blockIdx.x * 4 + (threadIdx.x >> 6);
  int lane = threadIdx.x & 63;
  if (wv >= B_ * R_) return;
  int b = wv / R_, r = wv % R_;
  int len = lens[b];
  float* row = abuf + ((size_t)b * R_ + r) * T_;
  float v[8];
  float mx = -1e30f;
#pragma unroll
  for (int i = 0; i < 8; ++i) {
    int t = lane + i * 64;
    float x = (t < len) ? row[t] : -1e30f;
    v[i] = x;
    mx = fmaxf(mx, x);
  }
#pragma unroll
  for (int o = 32; o > 0; o >>= 1) mx = fmaxf(mx, __shfl_xor(mx, o));
  float sum = 0.f;
#pragma unroll
  for (int i = 0; i < 8; ++i) {
    float e = (v[i] > -1e29f) ? __expf(v[i] - mx) : 0.f;
    v[i] = e;
    sum += e;
  }
#pragma unroll
  for (int o = 32; o > 0; o >>= 1) sum += __shfl_xor(sum, o);
  float inv = 1.f / sum;
#pragma unroll
  for (int i = 0; i < 8; ++i) row[lane + i * 64] = v[i] * inv;
}

// ---------------------------------------------------------------------------
// K6: M[b][r][h] = sum_t A[b][r][t] * out[b][t][h].
// ---------------------------------------------------------------------------
__global__ __launch_bounds__(256) void k6_m(const float* __restrict__ abuf,
                                            const unsigned short* __restrict__ outb,
                                            float* __restrict__ mbuf) {
  int b = blockIdx.x >> 4, hb = blockIdx.x & 15;
  __shared__ float As[R_ * T_];
  for (int i = threadIdx.x; i < R_ * T_; i += 256) As[i] = abuf[(size_t)b * R_ * T_ + i];
  __syncthreads();
  int h = threadIdx.x & 127, rh = threadIdx.x >> 7;
  float acc[15];
#pragma unroll
  for (int rr = 0; rr < 15; ++rr) acc[rr] = 0.f;
  const unsigned short* op = outb + (size_t)b * T_ * 2048 + hb * 128 + h;
  for (int t = 0; t < T_; ++t) {
    float vv = b2f(op[(size_t)t * 2048]);
#pragma unroll
    for (int rr = 0; rr < 15; ++rr) acc[rr] = fmaf(As[(rh * 15 + rr) * T_ + t], vv, acc[rr]);
  }
#pragma unroll
  for (int rr = 0; rr < 15; ++rr)
    mbuf[(size_t)b * FEAT_ + (size_t)(rh * 15 + rr) * 2048 + hb * 128 + h] = acc[rr];
}

// ---------------------------------------------------------------------------
// K7: per-sample penalty partial: ||A A^T - I||_F^2.
// ---------------------------------------------------------------------------
__global__ __launch_bounds__(256) void k7_pen(const float* __restrict__ abuf,
                                              float* __restrict__ penp) {
  int b = blockIdx.x;
  __shared__ float As[R_ * 515];
  __shared__ float red[256];
  for (int i = threadIdx.x; i < R_ * T_; i += 256) {
    int r = i >> 9, t = i & 511;
    As[r * 515 + t] = abuf[(size_t)b * R_ * T_ + i];
  }
  __syncthreads();
  float psum = 0.f;
  for (int p = threadIdx.x; p < R_ * R_; p += 256) {
    int r = p / R_, s = p % R_;
    const float* pr = As + r * 515;
    const float* ps = As + s * 515;
    float d = 0.f;
    for (int t = 0; t < T_; ++t) d = fmaf(pr[t], ps[t], d);
    d -= (r == s) ? 1.f : 0.f;
    psum += d * d;
  }
  red[threadIdx.x] = psum;
  __syncthreads();
  for (int o = 128; o > 0; o >>= 1) {
    if (threadIdx.x < o) red[threadIdx.x] += red[threadIdx.x + o];
    __syncthreads();
  }
  if (threadIdx.x == 0) penp[b] = red[0];
}

// ---------------------------------------------------------------------------
// K8: hid[b][m] = relu( feats[b][:] . W_mlp[m][:] + b_mlp[m] ).  (R1 form)
// ---------------------------------------------------------------------------
__global__ __launch_bounds__(256) void k8_mlp(const float* __restrict__ feats,
                                              const float* __restrict__ W_mlp,
                                              const float* __restrict__ b_mlp,
                                              float* __restrict__ hid) {
  int mblk = blockIdx.x >> 2, bblk = blockIdx.x & 3;
  int oi = threadIdx.x >> 1, ks = threadIdx.x & 1;
  int m = mblk * 16 + (oi >> 3);
  int b = bblk * 8 + (oi & 7);
  const float* fp = feats + (size_t)b * FEAT_;
  const float* wp = W_mlp + (size_t)m * FEAT_;
  float acc = 0.f;
  for (int i = 0; i < FEAT_ / 8; ++i) {
    int k = i * 8 + ks * 4;
    float4 wv = *(const float4*)(wp + k);
    float4 fv = *(const float4*)(fp + k);
    acc = fmaf(wv.x, fv.x, acc);
    acc = fmaf(wv.y, fv.y, acc);
    acc = fmaf(wv.z, fv.z, acc);
    acc = fmaf(wv.w, fv.w, acc);
  }
  float other = __shfl_xor(acc, 1);
  if (ks == 0) {
    float tot = acc + other + b_mlp[m];
    hid[(size_t)b * MH_ + m] = fmaxf(tot, 0.f);
  }
}

// ---------------------------------------------------------------------------
// K9: decoded = softmax(hid @ W_dec^T + b_dec); penal = mean(penp).
// ---------------------------------------------------------------------------
__global__ void k9_out(const float* __restrict__ hid, const float* __restrict__ W_dec,
                       const float* __restrict__ b_dec, const float* __restrict__ penp,
                       float* __restrict__ out) {
  int tid = threadIdx.x;
  if (tid < 64) {
    int b = tid >> 1, c = tid & 1;
    const float* hp = hid + (size_t)b * MH_;
    const float* wp = W_dec + (size_t)c * MH_;
    float acc = b_dec[c];
    for (int k = 0; k < MH_; ++k) acc = fmaf(hp[k], wp[k], acc);
    float other = __shfl_xor(acc, 1);
    float mx = fmaxf(acc, other);
    float e = __expf(acc - mx), eo = __expf(other - mx);
    out[b * 2 + c] = e / (e + eo);
  } else if (tid == 64) {
    float s = 0.f;
    for (int b = 0; b < B_; ++b) s += penp[b];
    out[64] = s * (1.f / 32.f);
  }
}

// ---------------------------------------------------------------------------
extern "C" void kernel_launch(void* const* d_in, const int* in_sizes, int n_in,
                              void* d_out, int out_size, void* d_ws, size_t ws_size,
                              hipStream_t stream) {
  const int* inp = (const int*)d_in[0];
  const int* lens = (const int*)d_in[1];
  const float* W_emb = (const float*)d_in[2];
  const float* W_ih = (const float*)d_in[3];
  const float* W_hh = (const float*)d_in[4];
  const float* b_ih = (const float*)d_in[5];
  const float* b_hh = (const float*)d_in[6];
  const float* W1 = (const float*)d_in[7];
  const float* W2 = (const float*)d_in[8];
  const float* W_mlp = (const float*)d_in[9];
  const float* b_mlp = (const float*)d_in[10];
  const float* W_dec = (const float*)d_in[11];
  const float* b_dec = (const float*)d_in[12];
  float* out = (float*)d_out;

  char* ws = (char*)d_ws;
  size_t off = 0;
  auto take = [&](size_t bytes) -> char* {
    char* p = ws + off;
    off = (off + bytes + 255) & ~(size_t)255;
    return p;
  };
  unsigned short* xw = (unsigned short*)take((size_t)T_ * 8192 * 32 * 2);       // 268.4 MB
  unsigned short* outb = (unsigned short*)take((size_t)B_ * T_ * 2048 * 2);     // 67.1 MB
  unsigned short* xb = (unsigned short*)take((size_t)16384 * KE_ * 2);          // 10.5 MB
  unsigned short* wihb = (unsigned short*)take((size_t)8192 * KE_ * 2);         // 5.2 MB
  unsigned short* w1b = (unsigned short*)take((size_t)AC_ * 2048 * 2);          // 1.6 MB
  unsigned short* th1 = (unsigned short*)take((size_t)16384 * AC_ * 2);         // 12.6 MB
  float* abuf = (float*)take((size_t)B_ * R_ * T_ * 4);                         // 2.0 MB
  float* mbuf = (float*)take((size_t)B_ * FEAT_ * 4);                           // 7.9 MB
  float* penp = (float*)take(B_ * 4);
  float* hid = (float*)take((size_t)B_ * MH_ * 4);

  if (off > ws_size) {  // unambiguous failure signal: NaN output
    hipMemsetAsync(d_out, 0xFF, (size_t)out_size * 4, stream);
    return;
  }

  // sentinel-init outb: 0xFFFF bf16 has bit14 set => "unwritten" marker
  hipMemsetAsync(outb, 0xFF, (size_t)B_ * T_ * 2048 * 2, stream);

  k0_prep<<<2048, 256, 0, stream>>>(inp, W_emb, W_ih, W1, xb, wihb, w1b);
  k1_xw<<<dim3(64, 128), 256, 0, stream>>>(wihb, xb, b_ih, b_hh, xw);
  k2_rnn<<<128, 256, 0, stream>>>(W_hh, xw, outb);
  k3_s1<<<512, 256, 0, stream>>>(outb, w1b, th1);
  k4_s2<<<2048, 256, 0, stream>>>(th1, W2, abuf);
  k5_sm<<<240, 256, 0, stream>>>(abuf, lens);
  k6_m<<<512, 256, 0, stream>>>(abuf, outb, mbuf);
  k7_pen<<<32, 256, 0, stream>>>(abuf, penp);
  k8_mlp<<<128, 256, 0, stream>>>(mbuf, W_mlp, b_mlp, hid);
  k9_out<<<1, 128, 0, stream>>>(hid, W_dec, b_dec, penp, out);
}

// Round 6
// 2899.202 us; speedup vs baseline: 1.7528x; 1.4391x over previous
//
#include <hip/hip_runtime.h>
#include <stdint.h>

typedef __attribute__((ext_vector_type(8))) short short8;
typedef __attribute__((ext_vector_type(4))) float f32x4;
typedef __attribute__((ext_vector_type(4))) unsigned int u32x4;

#define B_    32
#define T_    512
#define E_    300
#define KE_   384     // padded embed K (multiple of 128 for 4-wave x 32 split)
#define H_    1024
#define G4_   4096
#define R_    30
#define AD_   350
#define AC_   384
#define MH_   512
#define FEAT_ 61440
#define NWG_  64      // workgroups per direction
#define NU_   16      // hidden units per workgroup

__device__ __forceinline__ unsigned short f2bu(float f) {
  unsigned int x = __builtin_bit_cast(unsigned int, f);
  x += 0x7fffu + ((x >> 16) & 1u);
  return (unsigned short)(x >> 16);
}
__device__ __forceinline__ float b2f(unsigned short u) {
  return __builtin_bit_cast(float, (unsigned int)u << 16);
}
__device__ __forceinline__ float sigm(float x) {
  return __builtin_amdgcn_rcpf(1.f + __expf(-x));
}
__device__ __forceinline__ float tanh_fast(float x) {
  return 1.f - 2.f * __builtin_amdgcn_rcpf(1.f + __expf(2.f * x));
}

// ---------------------------------------------------------------------------
// K0: cast/pad to bf16: xb[16384][384], wihb[8192][384], w1b[384][2048],
//     wmlpb[512][61440]
// ---------------------------------------------------------------------------
__global__ void k0_prep(const int* __restrict__ inp, const float* __restrict__ W_emb,
                        const float* __restrict__ W_ih, const float* __restrict__ W1,
                        const float* __restrict__ W_mlp,
                        unsigned short* __restrict__ xb, unsigned short* __restrict__ wihb,
                        unsigned short* __restrict__ w1b, unsigned short* __restrict__ wmlpb) {
  const int N1 = 16384 * KE_;
  const int N2 = 8192 * KE_;
  const int N3 = AC_ * 2048;
  const int N4 = MH_ * FEAT_;
  const int NT = N1 + N2 + N3 + N4;
  for (int i = blockIdx.x * blockDim.x + threadIdx.x; i < NT; i += gridDim.x * blockDim.x) {
    if (i < N1) {
      int row = i / KE_, e = i - row * KE_;
      float v = (e < E_) ? W_emb[(size_t)inp[row] * E_ + e] : 0.f;
      xb[i] = f2bu(v);
    } else if (i < N1 + N2) {
      int j = i - N1;
      int rw = j / KE_, e = j - rw * KE_;
      float v = (e < E_) ? W_ih[(size_t)rw * E_ + e] : 0.f;
      wihb[j] = f2bu(v);
    } else if (i < N1 + N2 + N3) {
      int j = i - N1 - N2;
      int a = j >> 11, k = j & 2047;
      float v = (a < AD_) ? W1[(size_t)a * 2048 + k] : 0.f;
      w1b[j] = f2bu(v);
    } else {
      int j = i - N1 - N2 - N3;
      wmlpb[j] = f2bu(W_mlp[j]);
    }
  }
}

// ---------------------------------------------------------------------------
// K2 v6: persistent bidirectional LSTM, x-GEMM fused in, per-wave poll.
//   - W_hh quarter AND W_ih slice live in registers as bf16 A-frags
//   - x-GEMM (xb @ W_ih, K=384 split 4 ways) computed in the poll-wait shadow
//   - per-wave poll: wave wid waits only for its 16 K-quarter producers
//   - thin poll (sentinel bit14) -> cached bulk load -> validate -> backstop
// ---------------------------------------------------------------------------
__global__ __launch_bounds__(256, 1) void k2_rnn(const float* __restrict__ Whh,
                                                 const unsigned short* __restrict__ wihb,
                                                 const unsigned short* __restrict__ xb,
                                                 const float* __restrict__ b_ih,
                                                 const float* __restrict__ b_hh,
                                                 unsigned short* __restrict__ outb) {
  const int dir = blockIdx.x >> 6;
  const int w = blockIdx.x & 63;
  const int tid = threadIdx.x;
  const int wid = tid >> 6, lane = tid & 63;
  const int l15 = lane & 15, lg = lane >> 4;

  __shared__ float Gp[4][4][32][21];               // [wave][gate][batch][unit+pad21]
  __shared__ __align__(16) unsigned short htmp[32][16];

  // ---- preload W_hh K-quarter as bf16 A-frags (128 VGPR) ---------------
  short8 afr[4][8];
  {
    const int kq = wid << 8;
#pragma unroll
    for (int g = 0; g < 4; ++g) {
      const float* wp = Whh + ((size_t)dir * G4_ + g * H_ + w * NU_ + l15) * H_ + kq + lg * 8;
#pragma unroll
      for (int ktl = 0; ktl < 8; ++ktl) {
        float4 f0 = *(const float4*)(wp + ktl * 32);
        float4 f1 = *(const float4*)(wp + ktl * 32 + 4);
        short8 s;
        s[0] = (short)f2bu(f0.x); s[1] = (short)f2bu(f0.y);
        s[2] = (short)f2bu(f0.z); s[3] = (short)f2bu(f0.w);
        s[4] = (short)f2bu(f1.x); s[5] = (short)f2bu(f1.y);
        s[6] = (short)f2bu(f1.z); s[7] = (short)f2bu(f1.w);
        afr[g][ktl] = s;
      }
    }
  }

  // ---- preload W_ih K-slice (96 of 384) as bf16 A-frags (48 VGPR) ------
  const int kqx = wid * 96;
  short8 axr[4][3];
#pragma unroll
  for (int g = 0; g < 4; ++g) {
    const unsigned short* xp = wihb + ((size_t)dir * G4_ + g * H_ + w * NU_ + l15) * KE_ + kqx + lg * 8;
#pragma unroll
    for (int kt = 0; kt < 3; ++kt) axr[g][kt] = *(const short8*)(xp + kt * 32);
  }

  const int u = tid >> 5;    // activation role: unit pair (u, u+8)
  const int b = tid & 31;    // activation role: batch

  // ---- per-thread gate biases ------------------------------------------
  float bsum[2][4];
#pragma unroll
  for (int p = 0; p < 2; ++p)
#pragma unroll
    for (int g = 0; g < 4; ++g) {
      int row = dir * G4_ + g * H_ + w * NU_ + u + p * 8;
      bsum[p][g] = b_ih[row] + b_hh[row];
    }

  // B-fragment row base pointers into outb (batch rows l15 and l15+16)
  const unsigned short* rb0 = outb + (size_t)l15 * T_ * 2048 + dir * H_ + (wid << 8) + lg * 8;
  const unsigned short* rb1 = outb + (size_t)(l15 + 16) * T_ * 2048 + dir * H_ + (wid << 8) + lg * 8;

  float cst[2] = {0.f, 0.f};

#pragma unroll 1
  for (int s = 0; s < T_; ++s) {
    const int t = dir ? (T_ - 1 - s) : s;

    f32x4 acc[4][2];
#pragma unroll
    for (int g = 0; g < 4; ++g) {
      acc[g][0] = (f32x4){0.f, 0.f, 0.f, 0.f};
      acc[g][1] = (f32x4){0.f, 0.f, 0.f, 0.f};
    }

    // -- x-GEMM: runs in the shadow of peers publishing h(t-1) -----------
    {
      short8 xbf[2][3];
#pragma unroll
      for (int n = 0; n < 2; ++n)
#pragma unroll
        for (int kt = 0; kt < 3; ++kt)
          xbf[n][kt] = *(const short8*)(xb + ((size_t)(n * 16 + l15) * T_ + t) * KE_ + kqx + kt * 32 + lg * 8);
#pragma unroll
      for (int kt = 0; kt < 3; ++kt)
#pragma unroll
        for (int g = 0; g < 4; ++g) {
          acc[g][0] = __builtin_amdgcn_mfma_f32_16x16x32_bf16(axr[g][kt], xbf[0][kt], acc[g][0], 0, 0, 0);
          acc[g][1] = __builtin_amdgcn_mfma_f32_16x16x32_bf16(axr[g][kt], xbf[1][kt], acc[g][1], 0, 0, 0);
        }
    }
    __builtin_amdgcn_sched_barrier(0);   // keep x-GEMM before the poll

    if (s > 0) {
      const int tsrc = dir ? t + 1 : t - 1;

      // -- per-wave thin poll: only this wave's 16 K-quarter producers ----
      {
        const unsigned short* sp = outb + (size_t)tsrc * 2048 + dir * H_ + ((wid << 4) + l15) * NU_;
        unsigned v;
        int guard = 0;
        for (;;) {
          asm volatile("global_load_dword %0, %1, off sc0 sc1\n\ts_waitcnt vmcnt(0)"
                       : "=v"(v) : "v"(sp) : "memory");
          if (__all(!(v & 0x40004000u))) break;
          if (++guard > 50000) break;   // hang safety; never trips co-resident
        }
      }

      // -- bulk payload: ONE cached load pass (L2-dedup), then validate ---
      const unsigned short* a0 = rb0 + (size_t)tsrc * 2048;
      const unsigned short* a1 = rb1 + (size_t)tsrc * 2048;
      u32x4 q0, q1, q2, q3, q4, q5, q6, q7, q8, q9, qa, qb, qc, qd, qe, qf;
      q0 = *(const u32x4*)(a0 + 0 * 32);  q1 = *(const u32x4*)(a0 + 1 * 32);
      q2 = *(const u32x4*)(a0 + 2 * 32);  q3 = *(const u32x4*)(a0 + 3 * 32);
      q4 = *(const u32x4*)(a0 + 4 * 32);  q5 = *(const u32x4*)(a0 + 5 * 32);
      q6 = *(const u32x4*)(a0 + 6 * 32);  q7 = *(const u32x4*)(a0 + 7 * 32);
      q8 = *(const u32x4*)(a1 + 0 * 32);  q9 = *(const u32x4*)(a1 + 1 * 32);
      qa = *(const u32x4*)(a1 + 2 * 32);  qb = *(const u32x4*)(a1 + 3 * 32);
      qc = *(const u32x4*)(a1 + 4 * 32);  qd = *(const u32x4*)(a1 + 5 * 32);
      qe = *(const u32x4*)(a1 + 6 * 32);  qf = *(const u32x4*)(a1 + 7 * 32);
      {
        u32x4 o01 = q0 | q1, o23 = q2 | q3, o45 = q4 | q5, o67 = q6 | q7;
        u32x4 o89 = q8 | q9, oab = qa | qb, ocd = qc | qd, oef = qe | qf;
        u32x4 ov4 = ((o01 | o23) | (o45 | o67)) | ((o89 | oab) | (ocd | oef));
        unsigned ov = (ov4[0] | ov4[1]) | (ov4[2] | ov4[3]);
        if (__builtin_expect((ov & 0x40004000u) != 0, 0)) {
          // backstop: straggler store or stale L2 line -> sc0 sc1 reload loop
          int guard = 0;
          for (;;) {
            asm volatile(
                "global_load_dwordx4 %0, %16, off sc0 sc1\n\t"
                "global_load_dwordx4 %1, %16, off offset:64 sc0 sc1\n\t"
                "global_load_dwordx4 %2, %16, off offset:128 sc0 sc1\n\t"
                "global_load_dwordx4 %3, %16, off offset:192 sc0 sc1\n\t"
                "global_load_dwordx4 %4, %16, off offset:256 sc0 sc1\n\t"
                "global_load_dwordx4 %5, %16, off offset:320 sc0 sc1\n\t"
                "global_load_dwordx4 %6, %16, off offset:384 sc0 sc1\n\t"
                "global_load_dwordx4 %7, %16, off offset:448 sc0 sc1\n\t"
                "global_load_dwordx4 %8, %17, off sc0 sc1\n\t"
                "global_load_dwordx4 %9, %17, off offset:64 sc0 sc1\n\t"
                "global_load_dwordx4 %10, %17, off offset:128 sc0 sc1\n\t"
                "global_load_dwordx4 %11, %17, off offset:192 sc0 sc1\n\t"
                "global_load_dwordx4 %12, %17, off offset:256 sc0 sc1\n\t"
                "global_load_dwordx4 %13, %17, off offset:320 sc0 sc1\n\t"
                "global_load_dwordx4 %14, %17, off offset:384 sc0 sc1\n\t"
                "global_load_dwordx4 %15, %17, off offset:448 sc0 sc1\n\t"
                "s_waitcnt vmcnt(0)"
                : "=&v"(q0), "=&v"(q1), "=&v"(q2), "=&v"(q3), "=&v"(q4), "=&v"(q5),
                  "=&v"(q6), "=&v"(q7), "=&v"(q8), "=&v"(q9), "=&v"(qa), "=&v"(qb),
                  "=&v"(qc), "=&v"(qd), "=&v"(qe), "=&v"(qf)
                : "v"(a0), "v"(a1)
                : "memory");
            u32x4 r01 = q0 | q1, r23 = q2 | q3, r45 = q4 | q5, r67 = q6 | q7;
            u32x4 r89 = q8 | q9, rab = qa | qb, rcd = qc | qd, ref_ = qe | qf;
            u32x4 rv4 = ((r01 | r23) | (r45 | r67)) | ((r89 | rab) | (rcd | ref_));
            unsigned rv = (rv4[0] | rv4[1]) | (rv4[2] | rv4[3]);
            if (!(rv & 0x40004000u)) break;
            if (++guard > 50000) break;
          }
        }
      }

      short8 bf0[8], bf1[8];
      bf0[0] = __builtin_bit_cast(short8, q0); bf0[1] = __builtin_bit_cast(short8, q1);
      bf0[2] = __builtin_bit_cast(short8, q2); bf0[3] = __builtin_bit_cast(short8, q3);
      bf0[4] = __builtin_bit_cast(short8, q4); bf0[5] = __builtin_bit_cast(short8, q5);
      bf0[6] = __builtin_bit_cast(short8, q6); bf0[7] = __builtin_bit_cast(short8, q7);
      bf1[0] = __builtin_bit_cast(short8, q8); bf1[1] = __builtin_bit_cast(short8, q9);
      bf1[2] = __builtin_bit_cast(short8, qa); bf1[3] = __builtin_bit_cast(short8, qb);
      bf1[4] = __builtin_bit_cast(short8, qc); bf1[5] = __builtin_bit_cast(short8, qd);
      bf1[6] = __builtin_bit_cast(short8, qe); bf1[7] = __builtin_bit_cast(short8, qf);

#pragma unroll
      for (int ktl = 0; ktl < 8; ++ktl) {
#pragma unroll
        for (int g = 0; g < 4; ++g) {
          acc[g][0] = __builtin_amdgcn_mfma_f32_16x16x32_bf16(afr[g][ktl], bf0[ktl], acc[g][0], 0, 0, 0);
          acc[g][1] = __builtin_amdgcn_mfma_f32_16x16x32_bf16(afr[g][ktl], bf1[ktl], acc[g][1], 0, 0, 0);
        }
      }
    }

    // -- write K-partial sums to LDS (scalar, stride-21: conflict-free) --
#pragma unroll
    for (int g = 0; g < 4; ++g)
#pragma unroll
      for (int n = 0; n < 2; ++n)
#pragma unroll
        for (int j = 0; j < 4; ++j)
          Gp[wid][g][n * 16 + l15][lg * 4 + j] = acc[g][n][j];
    __syncthreads();

    // -- activations: thread handles (u,b) and (u+8,b) -------------------
#pragma unroll
    for (int p = 0; p < 2; ++p) {
      int ul = u + p * 8;
      float gi = Gp[0][0][b][ul] + Gp[1][0][b][ul] + Gp[2][0][b][ul] + Gp[3][0][b][ul] + bsum[p][0];
      float gf = Gp[0][1][b][ul] + Gp[1][1][b][ul] + Gp[2][1][b][ul] + Gp[3][1][b][ul] + bsum[p][1];
      float gg = Gp[0][2][b][ul] + Gp[1][2][b][ul] + Gp[2][2][b][ul] + Gp[3][2][b][ul] + bsum[p][2];
      float go = Gp[0][3][b][ul] + Gp[1][3][b][ul] + Gp[2][3][b][ul] + Gp[3][3][b][ul] + bsum[p][3];
      cst[p] = sigm(gf) * cst[p] + sigm(gi) * tanh_fast(gg);
      float hv = sigm(go) * tanh_fast(cst[p]);
      htmp[b][ul] = f2bu(hv);
    }
    __syncthreads();

    // -- wave 0: publish h into outb slot; the data IS the flag ----------
    if (tid < 64) {
      int bb = tid >> 1, half = tid & 1;
      u32x4 v = *(const u32x4*)&htmp[bb][half * 8];
      unsigned short* hp = outb + ((size_t)bb * T_ + t) * 2048 + dir * H_ + w * NU_ + half * 8;
      asm volatile("global_store_dwordx4 %0, %1, off sc0 sc1" :: "v"(hp), "v"(v) : "memory");
    }
  }
}

// ---------------------------------------------------------------------------
// K3: th1[row][a] = tanh( out[row][:] . W1b[a][:] )
// ---------------------------------------------------------------------------
__global__ __launch_bounds__(256, 1) void k3_s1(const unsigned short* __restrict__ outb,
                                                const unsigned short* __restrict__ w1b,
                                                unsigned short* __restrict__ th1) {
  const int rb = blockIdx.x;
  const int wid = threadIdx.x >> 6, lane = threadIdx.x & 63;
  const int m = wid & 1, nh = wid >> 1;
  const int l15 = lane & 15, lg = lane >> 4;

  f32x4 acc[12];
#pragma unroll
  for (int nt = 0; nt < 12; ++nt) acc[nt] = (f32x4){0.f, 0.f, 0.f, 0.f};

  const unsigned short* arow = outb + ((size_t)rb * 32 + m * 16 + l15) * 2048;
  for (int kt = 0; kt < 64; ++kt) {
    short8 af = *(const short8*)(arow + kt * 32 + lg * 8);
#pragma unroll
    for (int nt = 0; nt < 12; ++nt) {
      int col = nh * 192 + nt * 16 + l15;
      short8 bf = *(const short8*)(w1b + (size_t)col * 2048 + kt * 32 + lg * 8);
      acc[nt] = __builtin_amdgcn_mfma_f32_16x16x32_bf16(af, bf, acc[nt], 0, 0, 0);
    }
  }
#pragma unroll
  for (int nt = 0; nt < 12; ++nt) {
#pragma unroll
    for (int j = 0; j < 4; ++j) {
      int row = rb * 32 + m * 16 + lg * 4 + j;
      int col = nh * 192 + nt * 16 + l15;
      th1[(size_t)row * AC_ + col] = f2bu(tanh_fast(acc[nt][j]));
    }
  }
}

// ---------------------------------------------------------------------------
// K4: abuf[b][r][t] = th1[row][:350] . W2[r][:350]
// ---------------------------------------------------------------------------
__global__ void k4_s2(const unsigned short* __restrict__ th1, const float* __restrict__ W2,
                      float* __restrict__ abuf) {
  int idx = blockIdx.x * 256 + threadIdx.x;
  int row = idx >> 5, r = idx & 31;
  if (r >= R_) return;
  const unsigned short* tp = th1 + (size_t)row * AC_;
  const float* wp = W2 + r * AD_;
  float acc = 0.f;
  for (int a = 0; a < AD_; ++a) acc = fmaf(b2f(tp[a]), wp[a], acc);
  int b = row >> 9, t = row & 511;
  abuf[((size_t)b * R_ + r) * T_ + t] = acc;
}

// ---------------------------------------------------------------------------
// K5: masked softmax over t (in place).  One wave per (b,r).
// ---------------------------------------------------------------------------
__global__ void k5_sm(float* __restrict__ abuf, const int* __restrict__ lens) {
  int wv = blockIdx.x * 4 + (threadIdx.x >> 6);
  int lane = threadIdx.x & 63;
  if (wv >= B_ * R_) return;
  int b = wv / R_, r = wv % R_;
  int len = lens[b];
  float* row = abuf + ((size_t)b * R_ + r) * T_;
  float v[8];
  float mx = -1e30f;
#pragma unroll
  for (int i = 0; i < 8; ++i) {
    int t = lane + i * 64;
    float x = (t < len) ? row[t] : -1e30f;
    v[i] = x;
    mx = fmaxf(mx, x);
  }
#pragma unroll
  for (int o = 32; o > 0; o >>= 1) mx = fmaxf(mx, __shfl_xor(mx, o));
  float sum = 0.f;
#pragma unroll
  for (int i = 0; i < 8; ++i) {
    float e = (v[i] > -1e29f) ? __expf(v[i] - mx) : 0.f;
    v[i] = e;
    sum += e;
  }
#pragma unroll
  for (int o = 32; o > 0; o >>= 1) sum += __shfl_xor(sum, o);
  float inv = 1.f / sum;
#pragma unroll
  for (int i = 0; i < 8; ++i) row[lane + i * 64] = v[i] * inv;
}

// ---------------------------------------------------------------------------
// K6: M[b][r][h] = sum_t A[b][r][t] * out[b][t][h].  Writes mbuf as bf16.
// ---------------------------------------------------------------------------
__global__ __launch_bounds__(256) void k6_m(const float* __restrict__ abuf,
                                            const unsigned short* __restrict__ outb,
                                            unsigned short* __restrict__ mbuf) {
  int b = blockIdx.x >> 4, hb = blockIdx.x & 15;
  __shared__ float As[R_ * T_];
  for (int i = threadIdx.x; i < R_ * T_; i += 256) As[i] = abuf[(size_t)b * R_ * T_ + i];
  __syncthreads();
  int h = threadIdx.x & 127, rh = threadIdx.x >> 7;
  float acc[15];
#pragma unroll
  for (int rr = 0; rr < 15; ++rr) acc[rr] = 0.f;
  const unsigned short* op = outb + (size_t)b * T_ * 2048 + hb * 128 + h;
  for (int t = 0; t < T_; ++t) {
    float vv = b2f(op[(size_t)t * 2048]);
#pragma unroll
    for (int rr = 0; rr < 15; ++rr) acc[rr] = fmaf(As[(rh * 15 + rr) * T_ + t], vv, acc[rr]);
  }
#pragma unroll
  for (int rr = 0; rr < 15; ++rr)
    mbuf[(size_t)b * FEAT_ + (size_t)(rh * 15 + rr) * 2048 + hb * 128 + h] = f2bu(acc[rr]);
}

// ---------------------------------------------------------------------------
// K7: per-sample penalty partial: ||A A^T - I||_F^2.
// ---------------------------------------------------------------------------
__global__ __launch_bounds__(256) void k7_pen(const float* __restrict__ abuf,
                                              float* __restrict__ penp) {
  int b = blockIdx.x;
  __shared__ float As[R_ * 515];
  __shared__ float red[256];
  for (int i = threadIdx.x; i < R_ * T_; i += 256) {
    int r = i >> 9, t = i & 511;
    As[r * 515 + t] = abuf[(size_t)b * R_ * T_ + i];
  }
  __syncthreads();
  float psum = 0.f;
  for (int p = threadIdx.x; p < R_ * R_; p += 256) {
    int r = p / R_, s = p % R_;
    const float* pr = As + r * 515;
    const float* ps = As + s * 515;
    float d = 0.f;
    for (int t = 0; t < T_; ++t) d = fmaf(pr[t], ps[t], d);
    d -= (r == s) ? 1.f : 0.f;
    psum += d * d;
  }
  red[threadIdx.x] = psum;
  __syncthreads();
  for (int o = 128; o > 0; o >>= 1) {
    if (threadIdx.x < o) red[threadIdx.x] += red[threadIdx.x + o];
    __syncthreads();
  }
  if (threadIdx.x == 0) penp[b] = red[0];
}

// ---------------------------------------------------------------------------
// K8 v2: hidsum[b][m] += wmlpb[m-tile][k-tile] . mbuf[b][k-tile]  (MFMA)
//   grid = 16 mblk x 16 kblk; 4 waves K-split; LDS reduce; atomicAdd
// ---------------------------------------------------------------------------
__global__ __launch_bounds__(256, 1) void k8_mlp(const unsigned short* __restrict__ wmlpb,
                                                 const unsigned short* __restrict__ mbuf,
                                                 float* __restrict__ hid) {
  const int mblk = blockIdx.x >> 4, kblk = blockIdx.x & 15;
  const int wid = threadIdx.x >> 6, lane = threadIdx.x & 63;
  const int l15 = lane & 15, lg = lane >> 4;
  const int kq = kblk * 3840 + wid * 960;

  f32x4 acc[2][2];
#pragma unroll
  for (int i = 0; i < 2; ++i)
#pragma unroll
    for (int j = 0; j < 2; ++j) acc[i][j] = (f32x4){0.f, 0.f, 0.f, 0.f};

  const unsigned short* ap0 = wmlpb + (size_t)(mblk * 32 + l15) * FEAT_ + kq + lg * 8;
  const unsigned short* ap1 = ap0 + (size_t)16 * FEAT_;
  const unsigned short* bp0 = mbuf + (size_t)l15 * FEAT_ + kq + lg * 8;
  const unsigned short* bp1 = bp0 + (size_t)16 * FEAT_;
  for (int kt = 0; kt < 30; ++kt) {
    short8 a0 = *(const short8*)(ap0 + kt * 32);
    short8 a1 = *(const short8*)(ap1 + kt * 32);
    short8 b0 = *(const short8*)(bp0 + kt * 32);
    short8 b1 = *(const short8*)(bp1 + kt * 32);
    acc[0][0] = __builtin_amdgcn_mfma_f32_16x16x32_bf16(a0, b0, acc[0][0], 0, 0, 0);
    acc[0][1] = __builtin_amdgcn_mfma_f32_16x16x32_bf16(a0, b1, acc[0][1], 0, 0, 0);
    acc[1][0] = __builtin_amdgcn_mfma_f32_16x16x32_bf16(a1, b0, acc[1][0], 0, 0, 0);
    acc[1][1] = __builtin_amdgcn_mfma_f32_16x16x32_bf16(a1, b1, acc[1][1], 0, 0, 0);
  }

  __shared__ float red[4][32][33];
#pragma unroll
  for (int mi = 0; mi < 2; ++mi)
#pragma unroll
    for (int ni = 0; ni < 2; ++ni)
#pragma unroll
      for (int j = 0; j < 4; ++j)
        red[wid][mi * 16 + lg * 4 + j][ni * 16 + l15] = acc[mi][ni][j];
  __syncthreads();

  int m = threadIdx.x >> 3, b4 = (threadIdx.x & 7) * 4;
#pragma unroll
  for (int k = 0; k < 4; ++k) {
    int bb = b4 + k;
    float s = red[0][m][bb] + red[1][m][bb] + red[2][m][bb] + red[3][m][bb];
    atomicAdd(&hid[(size_t)bb * MH_ + mblk * 32 + m], s);
  }
}

// ---------------------------------------------------------------------------
// K9: decoded = softmax( relu(hid+b_mlp) @ W_dec^T + b_dec ); penal = mean.
// ---------------------------------------------------------------------------
__global__ void k9_out(const float* __restrict__ hid, const float* __restrict__ b_mlp,
                       const float* __restrict__ W_dec, const float* __restrict__ b_dec,
                       const float* __restrict__ penp, float* __restrict__ out) {
  int tid = threadIdx.x;
  if (tid < 64) {
    int b = tid >> 1, c = tid & 1;
    const float* hp = hid + (size_t)b * MH_;
    const float* wp = W_dec + (size_t)c * MH_;
    float acc = b_dec[c];
    for (int k = 0; k < MH_; ++k) {
      float hk = fmaxf(hp[k] + b_mlp[k], 0.f);
      acc = fmaf(hk, wp[k], acc);
    }
    float other = __shfl_xor(acc, 1);
    float mx = fmaxf(acc, other);
    float e = __expf(acc - mx), eo = __expf(other - mx);
    out[b * 2 + c] = e / (e + eo);
  } else if (tid == 64) {
    float s = 0.f;
    for (int b = 0; b < B_; ++b) s += penp[b];
    out[64] = s * (1.f / 32.f);
  }
}

// ---------------------------------------------------------------------------
extern "C" void kernel_launch(void* const* d_in, const int* in_sizes, int n_in,
                              void* d_out, int out_size, void* d_ws, size_t ws_size,
                              hipStream_t stream) {
  const int* inp = (const int*)d_in[0];
  const int* lens = (const int*)d_in[1];
  const float* W_emb = (const float*)d_in[2];
  const float* W_ih = (const float*)d_in[3];
  const float* W_hh = (const float*)d_in[4];
  const float* b_ih = (const float*)d_in[5];
  const float* b_hh = (const float*)d_in[6];
  const float* W1 = (const float*)d_in[7];
  const float* W2 = (const float*)d_in[8];
  const float* W_mlp = (const float*)d_in[9];
  const float* b_mlp = (const float*)d_in[10];
  const float* W_dec = (const float*)d_in[11];
  const float* b_dec = (const float*)d_in[12];
  float* out = (float*)d_out;

  char* ws = (char*)d_ws;
  size_t off = 0;
  auto take = [&](size_t bytes) -> char* {
    char* p = ws + off;
    off = (off + bytes + 255) & ~(size_t)255;
    return p;
  };
  unsigned short* outb = (unsigned short*)take((size_t)B_ * T_ * 2048 * 2);     // 67.1 MB
  unsigned short* xb = (unsigned short*)take((size_t)16384 * KE_ * 2);          // 12.6 MB
  unsigned short* wihb = (unsigned short*)take((size_t)8192 * KE_ * 2);         // 6.3 MB
  unsigned short* w1b = (unsigned short*)take((size_t)AC_ * 2048 * 2);          // 1.6 MB
  unsigned short* wmlpb = (unsigned short*)take((size_t)MH_ * FEAT_ * 2);       // 62.9 MB
  unsigned short* th1 = (unsigned short*)take((size_t)16384 * AC_ * 2);         // 12.6 MB
  float* abuf = (float*)take((size_t)B_ * R_ * T_ * 4);                         // 2.0 MB
  unsigned short* mbuf = (unsigned short*)take((size_t)B_ * FEAT_ * 2);         // 3.9 MB
  float* penp = (float*)take(B_ * 4);
  float* hid = (float*)take((size_t)B_ * MH_ * 4);

  if (off > ws_size) {  // unambiguous failure signal: NaN output
    hipMemsetAsync(d_out, 0xFF, (size_t)out_size * 4, stream);
    return;
  }

  // sentinel-init outb: 0xFFFF bf16 has bit14 set => "unwritten" marker
  hipMemsetAsync(outb, 0xFF, (size_t)B_ * T_ * 2048 * 2, stream);
  hipMemsetAsync(hid, 0, (size_t)B_ * MH_ * 4, stream);

  k0_prep<<<2048, 256, 0, stream>>>(inp, W_emb, W_ih, W1, W_mlp, xb, wihb, w1b, wmlpb);
  k2_rnn<<<128, 256, 0, stream>>>(W_hh, wihb, xb, b_ih, b_hh, outb);
  k3_s1<<<512, 256, 0, stream>>>(outb, w1b, th1);
  k4_s2<<<2048, 256, 0, stream>>>(th1, W2, abuf);
  k5_sm<<<240, 256, 0, stream>>>(abuf, lens);
  k6_m<<<512, 256, 0, stream>>>(abuf, outb, mbuf);
  k7_pen<<<32, 256, 0, stream>>>(abuf, penp);
  k8_mlp<<<256, 256, 0, stream>>>(wmlpb, mbuf, hid);
  k9_out<<<1, 128, 0, stream>>>(hid, b_mlp, W_dec, b_dec, penp, out);
}